// Round 1
// baseline (1410.788 us; speedup 1.0000x reference)
//
#include <hip/hip_runtime.h>
#include <math.h>

#define D_MODEL 1024
#define HIDDEN  2048
#define D_STATE 16
#define BATCH   2
#define SEQ     2048
#define NTOK    (BATCH*SEQ)   // 4096

__device__ __forceinline__ float softplus_f(float x) {
    return fmaxf(x, 0.0f) + log1pf(expf(-fabsf(x)));
}
__device__ __forceinline__ float sigmoid_f(float x) {
    return 1.0f / (1.0f + expf(-x));
}

// C[m,n] = sum_k A[m,k] * W[n,k]   (A:[M,K], W:[N,K], both row-major, K contiguous)
// MODE 0: out[m,n] = C + bias[n]
// MODE 1: out[m,n] = sigmoid(C + bias[n])
// MODE 2: atomicAdd(out[n], sum_m softplus(C + bias[n]))   (out = dt_sum[N])
// MODE 3: out[m,n] = C + bias[n] + aux[m,n]                (residual add)
template<int MODE>
__global__ __launch_bounds__(256) void proj_gemm(
    const float* __restrict__ A, const float* __restrict__ W,
    const float* __restrict__ bias, float* __restrict__ out,
    const float* __restrict__ aux, int M, int N, int K)
{
    // K-major-transposed tiles: As[kk][row], row-stride 68 floats (16B-aligned rows,
    // <=2-way bank aliasing on the transpose store which is free on CDNA4).
    __shared__ float As[16][68];
    __shared__ float Bs[16][68];

    const int tid = threadIdx.x;
    const int m0 = blockIdx.y * 64;
    const int n0 = blockIdx.x * 64;

    const int lrow = tid >> 2;        // 0..63
    const int lc4  = (tid & 3) * 4;   // 0,4,8,12

    const int tx = tid & 15, ty = tid >> 4;
    const int r0 = ty * 4, c0 = tx * 4;

    float acc[4][4] = {};

    for (int k0 = 0; k0 < K; k0 += 16) {
        float4 av = *reinterpret_cast<const float4*>(&A[(size_t)(m0 + lrow) * K + k0 + lc4]);
        float4 bv = *reinterpret_cast<const float4*>(&W[(size_t)(n0 + lrow) * K + k0 + lc4]);
        As[lc4 + 0][lrow] = av.x; As[lc4 + 1][lrow] = av.y;
        As[lc4 + 2][lrow] = av.z; As[lc4 + 3][lrow] = av.w;
        Bs[lc4 + 0][lrow] = bv.x; Bs[lc4 + 1][lrow] = bv.y;
        Bs[lc4 + 2][lrow] = bv.z; Bs[lc4 + 3][lrow] = bv.w;
        __syncthreads();
        #pragma unroll
        for (int kk = 0; kk < 16; kk++) {
            float4 a4 = *reinterpret_cast<const float4*>(&As[kk][r0]);
            float4 b4 = *reinterpret_cast<const float4*>(&Bs[kk][c0]);
            float a[4] = {a4.x, a4.y, a4.z, a4.w};
            float b[4] = {b4.x, b4.y, b4.z, b4.w};
            #pragma unroll
            for (int i = 0; i < 4; i++)
                #pragma unroll
                for (int j = 0; j < 4; j++)
                    acc[i][j] = fmaf(a[i], b[j], acc[i][j]);
        }
        __syncthreads();
    }

    if constexpr (MODE == 2) {
        __shared__ float red[16][64];
        #pragma unroll
        for (int j = 0; j < 4; j++) {
            float s = 0.f;
            float bj = bias[n0 + c0 + j];
            #pragma unroll
            for (int i = 0; i < 4; i++)
                s += softplus_f(acc[i][j] + bj);
            red[ty][c0 + j] = s;
        }
        __syncthreads();
        if (tid < 64) {
            float s = 0.f;
            #pragma unroll
            for (int t = 0; t < 16; t++) s += red[t][tid];
            atomicAdd(&out[n0 + tid], s);
        }
    } else {
        float b0 = bias[n0 + c0 + 0], b1 = bias[n0 + c0 + 1];
        float b2 = bias[n0 + c0 + 2], b3 = bias[n0 + c0 + 3];
        #pragma unroll
        for (int i = 0; i < 4; i++) {
            size_t off = (size_t)(m0 + r0 + i) * N + n0 + c0;
            float4 o;
            o.x = acc[i][0] + b0; o.y = acc[i][1] + b1;
            o.z = acc[i][2] + b2; o.w = acc[i][3] + b3;
            if constexpr (MODE == 1) {
                o.x = sigmoid_f(o.x); o.y = sigmoid_f(o.y);
                o.z = sigmoid_f(o.z); o.w = sigmoid_f(o.w);
            }
            if constexpr (MODE == 3) {
                const float4 ax = *reinterpret_cast<const float4*>(&aux[off]);
                o.x += ax.x; o.y += ax.y; o.z += ax.z; o.w += ax.w;
            }
            *reinterpret_cast<float4*>(&out[off]) = o;
        }
    }
}

// dt[h] = clamp(dt_sum[h]/NTOK, 1e-3, 2); A = -softplus(A_raw);
// A_d = exp(A*dt); B_d = (A_d-1)/(A+1e-6)*B_ssm     (one thread per (h,s))
__global__ __launch_bounds__(256) void dt_finalize(
    const float* __restrict__ dt_sum, const float* __restrict__ A_raw,
    const float* __restrict__ B_ssm, float* __restrict__ A_d, float* __restrict__ B_d)
{
    int i = blockIdx.x * 256 + threadIdx.x;
    if (i >= HIDDEN * D_STATE) return;
    int h = i >> 4;
    float dt = dt_sum[h] * (1.0f / NTOK);
    dt = fminf(fmaxf(dt, 1e-3f), 2.0f);
    float Av = -softplus_f(A_raw[i]);
    float Ad = expf(Av * dt);
    float Bd = (Ad - 1.0f) / (Av + 1e-6f) * B_ssm[i];
    A_d[i] = Ad;
    B_d[i] = Bd;
}

// uc = u*g + (conv3(u) + conv_b)*(1-g), written in place over g.
__global__ __launch_bounds__(256) void gate_conv_kernel(
    const float* __restrict__ u, float* g_io,
    const float* __restrict__ conv_w, const float* __restrict__ conv_b)
{
    size_t idx = (size_t)blockIdx.x * 256 + threadIdx.x;   // (n,h) flat
    int h = (int)(idx & (HIDDEN - 1));
    size_t n = idx >> 11;          // token 0..NTOK-1
    int l = (int)(n & (SEQ - 1));  // within-batch position
    float ucur  = u[idx];
    float uprev = (l > 0)       ? u[idx - HIDDEN] : 0.f;
    float unext = (l < SEQ - 1) ? u[idx + HIDDEN] : 0.f;
    float gv = g_io[idx];
    float conv = uprev * conv_w[h * 3 + 0] + ucur * conv_w[h * 3 + 1]
               + unext * conv_w[h * 3 + 2] + conv_b[h];
    g_io[idx] = ucur * gv + conv * (1.0f - gv);
}

// Selective scan: one thread per (b,h); state[S=16] in registers.
__global__ __launch_bounds__(256) void scan_kernel(
    const float* __restrict__ uc, const float* __restrict__ A_d,
    const float* __restrict__ B_d, const float* __restrict__ C_ssm,
    float* __restrict__ y)
{
    int t = blockIdx.x * 256 + threadIdx.x;   // 0..B*H-1
    int b = t >> 11;
    int h = t & (HIDDEN - 1);
    float Ad[D_STATE], Bd[D_STATE], Cv[D_STATE], st[D_STATE];
    #pragma unroll
    for (int s = 0; s < D_STATE; s++) {
        Ad[s] = A_d[h * D_STATE + s];
        Bd[s] = B_d[h * D_STATE + s];
        Cv[s] = C_ssm[h * D_STATE + s];
        st[s] = 0.f;
    }
    const float* ub = uc + (size_t)b * SEQ * HIDDEN + h;
    float* yb = y + (size_t)b * SEQ * HIDDEN + h;
    #pragma unroll 4
    for (int l = 0; l < SEQ; l++) {
        float uv = ub[(size_t)l * HIDDEN];
        float yv = 0.f;
        #pragma unroll
        for (int s = 0; s < D_STATE; s++) {
            st[s] = fmaf(Ad[s], st[s], Bd[s] * uv);
            yv = fmaf(st[s], Cv[s], yv);
        }
        yb[(size_t)l * HIDDEN] = yv;
    }
}

// LayerNorm over D_MODEL per row; block per row, 256 threads * float4.
__global__ __launch_bounds__(256) void ln_kernel(
    const float* __restrict__ resid, const float* __restrict__ ln_g,
    const float* __restrict__ ln_b, float* __restrict__ out)
{
    int row = blockIdx.x;
    int tid = threadIdx.x;
    const float4 v = reinterpret_cast<const float4*>(resid + (size_t)row * D_MODEL)[tid];
    float s  = v.x + v.y + v.z + v.w;
    float ss = v.x * v.x + v.y * v.y + v.z * v.z + v.w * v.w;
    #pragma unroll
    for (int off = 32; off > 0; off >>= 1) {
        s  += __shfl_down(s, off);
        ss += __shfl_down(ss, off);
    }
    __shared__ float sbuf[4], ssbuf[4];
    int wid = tid >> 6, lane = tid & 63;
    if (lane == 0) { sbuf[wid] = s; ssbuf[wid] = ss; }
    __syncthreads();
    float tot  = sbuf[0] + sbuf[1] + sbuf[2] + sbuf[3];
    float tot2 = ssbuf[0] + ssbuf[1] + ssbuf[2] + ssbuf[3];
    float mean = tot * (1.0f / D_MODEL);
    float var  = tot2 * (1.0f / D_MODEL) - mean * mean;
    float rstd = rsqrtf(var + 1e-5f);
    const float4 gv = reinterpret_cast<const float4*>(ln_g)[tid];
    const float4 bv = reinterpret_cast<const float4*>(ln_b)[tid];
    float4 o;
    o.x = (v.x - mean) * rstd * gv.x + bv.x;
    o.y = (v.y - mean) * rstd * gv.y + bv.y;
    o.z = (v.z - mean) * rstd * gv.z + bv.z;
    o.w = (v.w - mean) * rstd * gv.w + bv.w;
    reinterpret_cast<float4*>(out + (size_t)row * D_MODEL)[tid] = o;
}

extern "C" void kernel_launch(void* const* d_in, const int* in_sizes, int n_in,
                              void* d_out, int out_size, void* d_ws, size_t ws_size,
                              hipStream_t stream) {
    const float* x      = (const float*)d_in[0];
    const float* W_x    = (const float*)d_in[1];
    const float* b_x    = (const float*)d_in[2];
    const float* W_g    = (const float*)d_in[3];
    const float* b_g    = (const float*)d_in[4];
    const float* conv_w = (const float*)d_in[5];
    const float* conv_b = (const float*)d_in[6];
    const float* A_raw  = (const float*)d_in[7];
    const float* B_ssm  = (const float*)d_in[8];
    const float* C_ssm  = (const float*)d_in[9];
    const float* W_dt   = (const float*)d_in[10];
    const float* b_dt   = (const float*)d_in[11];
    const float* W_out  = (const float*)d_in[12];
    const float* b_out  = (const float*)d_in[13];
    const float* ln_g   = (const float*)d_in[14];
    const float* ln_b   = (const float*)d_in[15];

    float* ws     = (float*)d_ws;
    float* u_buf  = ws;                   // [NTOK, HIDDEN]  8388608 f
    float* g_buf  = ws + 8388608;         // [NTOK, HIDDEN]  8388608 f (→ uc → resid)
    float* dt_sum = ws + 16777216;        // [HIDDEN]
    float* A_d    = ws + 16779264;        // [HIDDEN, D_STATE]
    float* B_d    = ws + 16812032;        // [HIDDEN, D_STATE]
    float* y_buf  = u_buf;                // scan writes here (u dead after gate_conv)
    float* resid  = g_buf;                // out-GEMM writes here (uc dead after scan)

    hipMemsetAsync(dt_sum, 0, HIDDEN * sizeof(float), stream);

    dim3 blk(256);
    dim3 grid_proj(HIDDEN / 64, NTOK / 64);   // 32 x 64
    proj_gemm<0><<<grid_proj, blk, 0, stream>>>(x, W_x, b_x, u_buf, nullptr,
                                                NTOK, HIDDEN, D_MODEL);
    proj_gemm<1><<<grid_proj, blk, 0, stream>>>(x, W_g, b_g, g_buf, nullptr,
                                                NTOK, HIDDEN, D_MODEL);
    proj_gemm<2><<<grid_proj, blk, 0, stream>>>(x, W_dt, b_dt, dt_sum, nullptr,
                                                NTOK, HIDDEN, D_MODEL);
    dt_finalize<<<(HIDDEN * D_STATE) / 256, blk, 0, stream>>>(dt_sum, A_raw, B_ssm, A_d, B_d);
    gate_conv_kernel<<<((size_t)NTOK * HIDDEN) / 256, blk, 0, stream>>>(u_buf, g_buf,
                                                                        conv_w, conv_b);
    scan_kernel<<<(BATCH * HIDDEN) / 256, blk, 0, stream>>>(g_buf, A_d, B_d, C_ssm, y_buf);
    dim3 grid_out(D_MODEL / 64, NTOK / 64);   // 16 x 64
    proj_gemm<3><<<grid_out, blk, 0, stream>>>(y_buf, W_out, b_out, resid, x,
                                               NTOK, D_MODEL, HIDDEN);
    ln_kernel<<<NTOK, blk, 0, stream>>>(resid, ln_g, ln_b, (float*)d_out);
}

// Round 2
// 369.876 us; speedup vs baseline: 3.8142x; 3.8142x over previous
//
#include <hip/hip_runtime.h>
#include <math.h>

#define D_MODEL 1024
#define HIDDEN  2048
#define D_STATE 16
#define BATCH   2
#define SEQ     2048
#define NTOK    (BATCH*SEQ)   // 4096
#define CHUNK   64
#define NCHUNK  (SEQ/CHUNK)   // 32

typedef __attribute__((ext_vector_type(8))) short bf16x8;
typedef __attribute__((ext_vector_type(4))) float f32x4;

#define GLOAD_LDS16(gptr, lptr) \
    __builtin_amdgcn_global_load_lds((const __attribute__((address_space(1))) void*)(gptr), \
                                     (__attribute__((address_space(3))) void*)(lptr), 16, 0, 0)

__device__ __forceinline__ float softplus_f(float x) {
    return fmaxf(x, 0.0f) + log1pf(expf(-fabsf(x)));
}
__device__ __forceinline__ float sigmoid_f(float x) {
    return 1.0f / (1.0f + expf(-x));
}
__device__ __forceinline__ ushort f2bf(float f) {      // RNE fp32->bf16
    unsigned u = __float_as_uint(f);
    unsigned r = (u + 0x7fffu + ((u >> 16) & 1u)) >> 16;
    return (ushort)r;
}

__global__ __launch_bounds__(256) void cvt_bf16(const float* __restrict__ in,
                                                ushort* __restrict__ out, int n4) {
    int i = blockIdx.x * 256 + threadIdx.x;
    if (i >= n4) return;
    float4 v = reinterpret_cast<const float4*>(in)[i];
    ushort4 o = { f2bf(v.x), f2bf(v.y), f2bf(v.z), f2bf(v.w) };
    reinterpret_cast<ushort4*>(out)[i] = o;
}

// C[m,n] = sum_k A[m,k]*B[n,k], A:[M,K] bf16, B:[N,K] bf16 (both K-contiguous).
// 128x128 tile, BK=32, 4 waves in 2x2 grid, each wave 64x64 via 4x4 16x16x32 MFMAs.
// MODE 0: out[m,n]=C+bias[n]           (fp32)
// MODE 1: out[m,n]=sigmoid(C+bias[n])
// MODE 2: atomicAdd(out[n], sum_m softplus(C+bias[n]))
// MODE 3: out[m,n]=C+bias[n]+aux[m,n]
template<int MODE>
__global__ __launch_bounds__(256) void gemm_bf16(
    const ushort* __restrict__ A, const ushort* __restrict__ B,
    const float* __restrict__ bias, float* __restrict__ out,
    const float* __restrict__ aux, int M, int N, int K)
{
    __shared__ ushort As[128 * 32];
    __shared__ ushort Bs[128 * 32];

    const int tid  = threadIdx.x;
    const int lane = tid & 63;
    const int w    = tid >> 6;
    const int m0   = blockIdx.y * 128;
    const int n0   = blockIdx.x * 128;
    const int wm   = w & 1, wn = w >> 1;

    f32x4 acc[4][4];
    #pragma unroll
    for (int i = 0; i < 4; i++)
        #pragma unroll
        for (int j = 0; j < 4; j++)
            acc[i][j] = (f32x4){0.f, 0.f, 0.f, 0.f};

    const int koff = (lane >> 4) * 8;      // frag k offset (quad*8)
    const int fr   = lane & 15;            // frag row/col within 16

    for (int k0 = 0; k0 < K; k0 += 32) {
        // stage 128x32 bf16 tiles of A and B via global_load_lds width=16
        #pragma unroll
        for (int j = 0; j < 2; j++) {
            const int sb  = (w * 2 + j) * 64;            // wave-uniform slot base
            const int row = (w * 2 + j) * 16 + (lane >> 2);
            const int kc  = (lane & 3) * 8;
            const ushort* ga = A + (size_t)(m0 + row) * K + k0 + kc;
            const ushort* gb = B + (size_t)(n0 + row) * K + k0 + kc;
            GLOAD_LDS16(ga, &As[sb * 8]);
            GLOAD_LDS16(gb, &Bs[sb * 8]);
        }
        __syncthreads();
        bf16x8 af[4], bfr[4];
        #pragma unroll
        for (int t = 0; t < 4; t++) {
            af[t]  = *reinterpret_cast<const bf16x8*>(&As[(wm * 64 + t * 16 + fr) * 32 + koff]);
            bfr[t] = *reinterpret_cast<const bf16x8*>(&Bs[(wn * 64 + t * 16 + fr) * 32 + koff]);
        }
        #pragma unroll
        for (int i = 0; i < 4; i++)
            #pragma unroll
            for (int j = 0; j < 4; j++)
                acc[i][j] = __builtin_amdgcn_mfma_f32_16x16x32_bf16(af[i], bfr[j], acc[i][j], 0, 0, 0);
        __syncthreads();
    }

    // C/D layout: col = lane&15, row = (lane>>4)*4 + reg
    if constexpr (MODE == 2) {
        #pragma unroll
        for (int j = 0; j < 4; j++) {
            int n = n0 + wn * 64 + j * 16 + fr;
            float bj = bias[n];
            float s = 0.f;
            #pragma unroll
            for (int i = 0; i < 4; i++)
                #pragma unroll
                for (int r = 0; r < 4; r++)
                    s += softplus_f(acc[i][j][r] + bj);
            s += __shfl_xor(s, 16);
            s += __shfl_xor(s, 32);
            if (lane < 16) atomicAdd(&out[n], s);
        }
    } else {
        #pragma unroll
        for (int j = 0; j < 4; j++) {
            int n = n0 + wn * 64 + j * 16 + fr;
            float bj = bias[n];
            #pragma unroll
            for (int i = 0; i < 4; i++) {
                int mrow = m0 + wm * 64 + i * 16 + ((lane >> 4) << 2);
                #pragma unroll
                for (int r = 0; r < 4; r++) {
                    float v = acc[i][j][r] + bj;
                    if constexpr (MODE == 1) v = sigmoid_f(v);
                    size_t off = (size_t)(mrow + r) * N + n;
                    if constexpr (MODE == 3) v += aux[off];
                    out[off] = v;
                }
            }
        }
    }
}

// dt[h]=clamp(dt_sum[h]/NTOK,1e-3,2); A=-softplus(A_raw); A_d=exp(A*dt);
// B_d=(A_d-1)/(A+1e-6)*B_ssm; A_dL=A_d^CHUNK
__global__ __launch_bounds__(256) void dt_finalize(
    const float* __restrict__ dt_sum, const float* __restrict__ A_raw,
    const float* __restrict__ B_ssm, float* __restrict__ A_d,
    float* __restrict__ B_d, float* __restrict__ A_dL)
{
    int i = blockIdx.x * 256 + threadIdx.x;
    if (i >= HIDDEN * D_STATE) return;
    int h = i >> 4;
    float dt = dt_sum[h] * (1.0f / NTOK);
    dt = fminf(fmaxf(dt, 1e-3f), 2.0f);
    float Av = -softplus_f(A_raw[i]);
    float Ad = expf(Av * dt);
    float Bd = (Ad - 1.0f) / (Av + 1e-6f) * B_ssm[i];
    A_d[i] = Ad;
    B_d[i] = Bd;
    A_dL[i] = expf(Av * dt * CHUNK);
}

// uc = u*g + (conv3(u)+conv_b)*(1-g), in place over g.
__global__ __launch_bounds__(256) void gate_conv_kernel(
    const float* __restrict__ u, float* g_io,
    const float* __restrict__ conv_w, const float* __restrict__ conv_b)
{
    size_t idx = (size_t)blockIdx.x * 256 + threadIdx.x;
    int h = (int)(idx & (HIDDEN - 1));
    size_t n = idx >> 11;
    int l = (int)(n & (SEQ - 1));
    float ucur  = u[idx];
    float uprev = (l > 0)       ? u[idx - HIDDEN] : 0.f;
    float unext = (l < SEQ - 1) ? u[idx + HIDDEN] : 0.f;
    float gv = g_io[idx];
    float conv = uprev * conv_w[h * 3 + 0] + ucur * conv_w[h * 3 + 1]
               + unext * conv_w[h * 3 + 2] + conv_b[h];
    g_io[idx] = ucur * gv + conv * (1.0f - gv);
}

// Pass 1: per-(b,chunk,h) local scan from zero state; writes partial y (fp32)
// and chunk-final local state.
__global__ __launch_bounds__(256) void scan_pass1(
    const float* __restrict__ uc, const float* __restrict__ A_d,
    const float* __restrict__ B_d, const float* __restrict__ C_ssm,
    float* __restrict__ ypart, float* __restrict__ states)
{
    int idx = blockIdx.x * 256 + threadIdx.x;   // h fastest
    int h  = idx & (HIDDEN - 1);
    int bc = idx >> 11;                          // b*NCHUNK + c
    int c  = bc & (NCHUNK - 1);
    int b  = bc >> 5;                            // log2(NCHUNK)=5
    float Ad[D_STATE], Bd[D_STATE], Cv[D_STATE], st[D_STATE];
    const float4* a4 = reinterpret_cast<const float4*>(A_d  + h * D_STATE);
    const float4* b4 = reinterpret_cast<const float4*>(B_d  + h * D_STATE);
    const float4* c4 = reinterpret_cast<const float4*>(C_ssm + h * D_STATE);
    #pragma unroll
    for (int q = 0; q < 4; q++) {
        float4 av = a4[q], bv = b4[q], cv = c4[q];
        Ad[q*4+0]=av.x; Ad[q*4+1]=av.y; Ad[q*4+2]=av.z; Ad[q*4+3]=av.w;
        Bd[q*4+0]=bv.x; Bd[q*4+1]=bv.y; Bd[q*4+2]=bv.z; Bd[q*4+3]=bv.w;
        Cv[q*4+0]=cv.x; Cv[q*4+1]=cv.y; Cv[q*4+2]=cv.z; Cv[q*4+3]=cv.w;
    }
    #pragma unroll
    for (int s = 0; s < D_STATE; s++) st[s] = 0.f;
    const size_t base = ((size_t)b * SEQ + (size_t)c * CHUNK) * HIDDEN + h;
    for (int l = 0; l < CHUNK; l++) {
        float uv = uc[base + (size_t)l * HIDDEN];
        float yv = 0.f;
        #pragma unroll
        for (int s = 0; s < D_STATE; s++) {
            st[s] = fmaf(Ad[s], st[s], Bd[s] * uv);
            yv = fmaf(st[s], Cv[s], yv);
        }
        ypart[base + (size_t)l * HIDDEN] = yv;
    }
    float4* sp = reinterpret_cast<float4*>(states + ((size_t)bc * HIDDEN + h) * D_STATE);
    #pragma unroll
    for (int q = 0; q < 4; q++)
        sp[q] = (float4){st[q*4+0], st[q*4+1], st[q*4+2], st[q*4+3]};
}

// Pass 2: propagate chunk-boundary states (in place: states[c] becomes the
// INCOMING state for chunk c). One thread per (b,h,s).
__global__ __launch_bounds__(256) void scan_pass2(
    float* __restrict__ states, const float* __restrict__ A_dL)
{
    int idx = blockIdx.x * 256 + threadIdx.x;
    int s = idx & 15;
    int h = (idx >> 4) & (HIDDEN - 1);
    int b = idx >> 15;
    float aL = A_dL[h * D_STATE + s];
    float carry = 0.f;
    for (int c = 0; c < NCHUNK; c++) {
        size_t addr = (((size_t)(b * NCHUNK + c) * HIDDEN) + h) * D_STATE + s;
        float fin = states[addr];
        states[addr] = carry;
        carry = fmaf(aL, carry, fin);
    }
}

// Pass 3: y_true[l] = y_local[l] + sum_s C[s]*A_d[s]^(l+1)*s_in[s]; emits bf16.
__global__ __launch_bounds__(256) void scan_pass3(
    const float* __restrict__ ypart, const float* __restrict__ states,
    const float* __restrict__ A_d, const float* __restrict__ C_ssm,
    ushort* __restrict__ ybf)
{
    int idx = blockIdx.x * 256 + threadIdx.x;
    int h  = idx & (HIDDEN - 1);
    int bc = idx >> 11;
    int c  = bc & (NCHUNK - 1);
    int b  = bc >> 5;
    float Ad[D_STATE], t[D_STATE];
    const float* sp = states + ((size_t)bc * HIDDEN + h) * D_STATE;
    #pragma unroll
    for (int s = 0; s < D_STATE; s++) {
        float a = A_d[h * D_STATE + s];
        Ad[s] = a;
        t[s] = C_ssm[h * D_STATE + s] * a * sp[s];
    }
    const size_t base = ((size_t)b * SEQ + (size_t)c * CHUNK) * HIDDEN + h;
    for (int l = 0; l < CHUNK; l++) {
        float corr = 0.f;
        #pragma unroll
        for (int s = 0; s < D_STATE; s++) {
            corr += t[s];
            t[s] *= Ad[s];
        }
        float y = ypart[base + (size_t)l * HIDDEN] + corr;
        ybf[base + (size_t)l * HIDDEN] = f2bf(y);
    }
}

__global__ __launch_bounds__(256) void ln_kernel(
    const float* __restrict__ resid, const float* __restrict__ ln_g,
    const float* __restrict__ ln_b, float* __restrict__ out)
{
    int row = blockIdx.x;
    int tid = threadIdx.x;
    const float4 v = reinterpret_cast<const float4*>(resid + (size_t)row * D_MODEL)[tid];
    float s  = v.x + v.y + v.z + v.w;
    float ss = v.x * v.x + v.y * v.y + v.z * v.z + v.w * v.w;
    #pragma unroll
    for (int off = 32; off > 0; off >>= 1) {
        s  += __shfl_down(s, off);
        ss += __shfl_down(ss, off);
    }
    __shared__ float sbuf[4], ssbuf[4];
    int wid = tid >> 6, lane = tid & 63;
    if (lane == 0) { sbuf[wid] = s; ssbuf[wid] = ss; }
    __syncthreads();
    float tot  = sbuf[0] + sbuf[1] + sbuf[2] + sbuf[3];
    float tot2 = ssbuf[0] + ssbuf[1] + ssbuf[2] + ssbuf[3];
    float mean = tot * (1.0f / D_MODEL);
    float var  = tot2 * (1.0f / D_MODEL) - mean * mean;
    float rstd = rsqrtf(var + 1e-5f);
    const float4 gv = reinterpret_cast<const float4*>(ln_g)[tid];
    const float4 bv = reinterpret_cast<const float4*>(ln_b)[tid];
    float4 o;
    o.x = (v.x - mean) * rstd * gv.x + bv.x;
    o.y = (v.y - mean) * rstd * gv.y + bv.y;
    o.z = (v.z - mean) * rstd * gv.z + bv.z;
    o.w = (v.w - mean) * rstd * gv.w + bv.w;
    reinterpret_cast<float4*>(out + (size_t)row * D_MODEL)[tid] = o;
}

extern "C" void kernel_launch(void* const* d_in, const int* in_sizes, int n_in,
                              void* d_out, int out_size, void* d_ws, size_t ws_size,
                              hipStream_t stream) {
    const float* x      = (const float*)d_in[0];
    const float* W_x    = (const float*)d_in[1];
    const float* b_x    = (const float*)d_in[2];
    const float* W_g    = (const float*)d_in[3];
    const float* b_g    = (const float*)d_in[4];
    const float* conv_w = (const float*)d_in[5];
    const float* conv_b = (const float*)d_in[6];
    const float* A_raw  = (const float*)d_in[7];
    const float* B_ssm  = (const float*)d_in[8];
    const float* C_ssm  = (const float*)d_in[9];
    const float* W_dt   = (const float*)d_in[10];
    const float* b_dt   = (const float*)d_in[11];
    const float* W_out  = (const float*)d_in[12];
    const float* b_out  = (const float*)d_in[13];
    const float* ln_g   = (const float*)d_in[14];
    const float* ln_b   = (const float*)d_in[15];

    char* W = (char*)d_ws;
    float*  u_buf   = (float*)(W);                         // 32MB [NTOK,HIDDEN]
    float*  g_buf   = (float*)(W + (32ull << 20));         // 32MB (g -> uc -> resid)
    ushort* x_bf    = (ushort*)(W + (64ull << 20));        // 8MB
    ushort* Wx_bf   = (ushort*)(W + (72ull << 20));        // 4MB
    ushort* Wg_bf   = (ushort*)(W + (76ull << 20));        // 4MB
    ushort* Wdt_bf  = (ushort*)(W + (80ull << 20));        // 4MB
    ushort* Wout_bf = (ushort*)(W + (84ull << 20));        // 4MB
    float*  states  = (float*)(W + (88ull << 20));         // 8MB [B*NC,H,16]
    float*  dt_sum  = (float*)(W + (96ull << 20));         // 8KB
    float*  A_d     = (float*)(W + (96ull << 20) + 65536);  // 128KB
    float*  B_d     = (float*)(W + (96ull << 20) + 65536 + 131072);
    float*  A_dL    = (float*)(W + (96ull << 20) + 65536 + 262144);
    ushort* y_bf    = (ushort*)(W + (64ull << 20));        // 16MB, aliases x_bf/Wx/Wg (dead)
    float*  ypart   = u_buf;                               // aliases u (dead after gate_conv)
    float*  resid   = g_buf;                               // aliases uc (dead after pass1)

    hipMemsetAsync(dt_sum, 0, HIDDEN * sizeof(float), stream);

    dim3 blk(256);
    // fp32 -> bf16 converts
    cvt_bf16<<<(NTOK * D_MODEL / 4 + 255) / 256, blk, 0, stream>>>(x, x_bf, NTOK * D_MODEL / 4);
    cvt_bf16<<<(HIDDEN * D_MODEL / 4 + 255) / 256, blk, 0, stream>>>(W_x, Wx_bf, HIDDEN * D_MODEL / 4);
    cvt_bf16<<<(HIDDEN * D_MODEL / 4 + 255) / 256, blk, 0, stream>>>(W_g, Wg_bf, HIDDEN * D_MODEL / 4);
    cvt_bf16<<<(HIDDEN * D_MODEL / 4 + 255) / 256, blk, 0, stream>>>(W_dt, Wdt_bf, HIDDEN * D_MODEL / 4);
    cvt_bf16<<<(D_MODEL * HIDDEN / 4 + 255) / 256, blk, 0, stream>>>(W_out, Wout_bf, D_MODEL * HIDDEN / 4);

    dim3 grid_proj(HIDDEN / 128, NTOK / 128);   // 16 x 32
    gemm_bf16<0><<<grid_proj, blk, 0, stream>>>(x_bf, Wx_bf, b_x, u_buf, nullptr,
                                                NTOK, HIDDEN, D_MODEL);
    gemm_bf16<1><<<grid_proj, blk, 0, stream>>>(x_bf, Wg_bf, b_g, g_buf, nullptr,
                                                NTOK, HIDDEN, D_MODEL);
    gemm_bf16<2><<<grid_proj, blk, 0, stream>>>(x_bf, Wdt_bf, b_dt, dt_sum, nullptr,
                                                NTOK, HIDDEN, D_MODEL);
    dt_finalize<<<(HIDDEN * D_STATE) / 256, blk, 0, stream>>>(dt_sum, A_raw, B_ssm,
                                                              A_d, B_d, A_dL);
    gate_conv_kernel<<<((size_t)NTOK * HIDDEN) / 256, blk, 0, stream>>>(u_buf, g_buf,
                                                                        conv_w, conv_b);
    scan_pass1<<<(BATCH * NCHUNK * HIDDEN) / 256, blk, 0, stream>>>(g_buf, A_d, B_d, C_ssm,
                                                                    ypart, states);
    scan_pass2<<<(BATCH * HIDDEN * D_STATE) / 256, blk, 0, stream>>>(states, A_dL);
    scan_pass3<<<(BATCH * NCHUNK * HIDDEN) / 256, blk, 0, stream>>>(ypart, states, A_d,
                                                                    C_ssm, y_bf);
    dim3 grid_out(D_MODEL / 128, NTOK / 128);   // 8 x 32
    gemm_bf16<3><<<grid_out, blk, 0, stream>>>(y_bf, Wout_bf, b_out, resid, x,
                                               NTOK, D_MODEL, HIDDEN);
    ln_kernel<<<NTOK, blk, 0, stream>>>(resid, ln_g, ln_b, (float*)d_out);
}

// Round 3
// 350.738 us; speedup vs baseline: 4.0223x; 1.0546x over previous
//
#include <hip/hip_runtime.h>
#include <math.h>

#define D_MODEL 1024
#define HIDDEN  2048
#define D_STATE 16
#define BATCH   2
#define SEQ     2048
#define NTOK    (BATCH*SEQ)   // 4096
#define CHUNK   64
#define NCHUNK  (SEQ/CHUNK)   // 32

typedef __attribute__((ext_vector_type(8))) short bf16x8;
typedef __attribute__((ext_vector_type(4))) float f32x4;

#define GLOAD_LDS16(gptr, lptr) \
    __builtin_amdgcn_global_load_lds((const __attribute__((address_space(1))) void*)(gptr), \
                                     (__attribute__((address_space(3))) void*)(lptr), 16, 0, 0)

__device__ __forceinline__ float softplus_f(float x) {
    return fmaxf(x, 0.0f) + log1pf(expf(-fabsf(x)));
}
__device__ __forceinline__ float sigmoid_f(float x) {
    return 1.0f / (1.0f + expf(-x));
}
__device__ __forceinline__ ushort f2bf(float f) {      // RNE fp32->bf16
    unsigned u = __float_as_uint(f);
    unsigned r = (u + 0x7fffu + ((u >> 16) & 1u)) >> 16;
    return (ushort)r;
}
__device__ __forceinline__ float bf2f(ushort u) {
    return __uint_as_float(((unsigned)u) << 16);
}

// One kernel converts x, W_x, W_g, W_dt, W_out into a contiguous bf16 arena:
// [x (4M f4) | Wx (0.5M) | Wg (0.5M) | Wdt (0.5M) | Wout (0.5M)] in float4 units.
__global__ __launch_bounds__(256) void cvt_all(
    const float* __restrict__ x, const float* __restrict__ Wx,
    const float* __restrict__ Wg, const float* __restrict__ Wdt,
    const float* __restrict__ Wout, ushort* __restrict__ arena)
{
    int i = blockIdx.x * 256 + threadIdx.x;   // float4 index, total 3145728
    const float* src; int base;
    if      (i < 1048576) { src = x;    base = 0; }
    else if (i < 1572864) { src = Wx;   base = 1048576; }
    else if (i < 2097152) { src = Wg;   base = 1572864; }
    else if (i < 2621440) { src = Wdt;  base = 2097152; }
    else                  { src = Wout; base = 2621440; }
    float4 v = reinterpret_cast<const float4*>(src)[i - base];
    ushort4 o = { f2bf(v.x), f2bf(v.y), f2bf(v.z), f2bf(v.w) };
    reinterpret_cast<ushort4*>(arena)[i] = o;
}

// Shared K-loop: C[128,128] += A[128,K] * B[128,K]^T tiles, BK=32.
// LDS layout is XOR-swizzled: row r's logical 16B-chunk q lives at physical
// slot p = (q + (r>>2)) & 3. global_load_lds deposits lane i at base+i*16, so
// the swizzle is applied by permuting each lane's GLOBAL source chunk. Reading
// a fragment (16 lanes, rows r=0..15 mod 16, chunk q=quad) then spreads the 16
// granules 2-per-bank-group -> 2-way aliasing only (free on CDNA4).
__device__ __forceinline__ void kloop_128(
    const ushort* __restrict__ A, const ushort* __restrict__ B,
    int K, int m0, int n0, ushort* As, ushort* Bs,
    f32x4 (&acc)[4][4], int lane, int w, int wm, int wn)
{
    const int lr   = lane >> 2;            // row within 16-row slab
    const int p    = lane & 3;             // physical chunk slot
    const int quad = lane >> 4;
    const int fr   = lane & 15;
    for (int k0 = 0; k0 < K; k0 += 32) {
        #pragma unroll
        for (int j = 0; j < 2; j++) {
            const int slab = w * 2 + j;               // 0..7
            const int r    = slab * 16 + lr;          // tile-local row
            const int q    = (p - (r >> 2)) & 3;      // logical chunk this lane fetches
            const ushort* ga = A + (size_t)(m0 + r) * K + k0 + q * 8;
            const ushort* gb = B + (size_t)(n0 + r) * K + k0 + q * 8;
            GLOAD_LDS16(ga, &As[slab * 512]);
            GLOAD_LDS16(gb, &Bs[slab * 512]);
        }
        __syncthreads();
        bf16x8 af[4], bfv[4];
        #pragma unroll
        for (int t = 0; t < 4; t++) {
            int ra = wm * 64 + t * 16 + fr;
            int pa = (quad + (ra >> 2)) & 3;
            af[t]  = *reinterpret_cast<const bf16x8*>(&As[ra * 32 + pa * 8]);
            int rb = wn * 64 + t * 16 + fr;
            int pb = (quad + (rb >> 2)) & 3;
            bfv[t] = *reinterpret_cast<const bf16x8*>(&Bs[rb * 32 + pb * 8]);
        }
        #pragma unroll
        for (int i = 0; i < 4; i++)
            #pragma unroll
            for (int j = 0; j < 4; j++)
                acc[i][j] = __builtin_amdgcn_mfma_f32_16x16x32_bf16(af[i], bfv[j], acc[i][j], 0, 0, 0);
        __syncthreads();
    }
}

// Fused projection GEMM: A = x_bf [NTOK,1024], B = Wcat [6144,1024].
// Region by column block: [0,2048)->u (bf16), [2048,4096)->sigmoid->g (bf16),
// [4096,6144)->softplus column-reduce -> atomicAdd dt_sum.
__global__ __launch_bounds__(256) void proj_gemm_fused(
    const ushort* __restrict__ xbf, const ushort* __restrict__ Wcat,
    const float* __restrict__ b_x, const float* __restrict__ b_g,
    const float* __restrict__ b_dt, ushort* __restrict__ u_out,
    ushort* __restrict__ g_out, float* __restrict__ dt_sum)
{
    __shared__ ushort As[128 * 32];
    __shared__ ushort Bs[128 * 32];
    const int tid = threadIdx.x, lane = tid & 63, w = tid >> 6;
    const int wm = w & 1, wn = w >> 1;
    const int m0 = blockIdx.y * 128, n0 = blockIdx.x * 128;
    const int quad = lane >> 4, fr = lane & 15;

    f32x4 acc[4][4];
    #pragma unroll
    for (int i = 0; i < 4; i++)
        #pragma unroll
        for (int j = 0; j < 4; j++)
            acc[i][j] = (f32x4){0.f, 0.f, 0.f, 0.f};

    kloop_128(xbf, Wcat, D_MODEL, m0, n0, As, Bs, acc, lane, w, wm, wn);

    const int region = n0 >> 11;           // 0:u 1:g 2:dt
    const int nc0 = (n0 & 2047) + wn * 64; // local col base

    if (region == 2) {
        #pragma unroll
        for (int j = 0; j < 4; j++) {
            int n = nc0 + j * 16 + fr;
            float bj = b_dt[n];
            float s = 0.f;
            #pragma unroll
            for (int i = 0; i < 4; i++)
                #pragma unroll
                for (int r = 0; r < 4; r++)
                    s += softplus_f(acc[i][j][r] + bj);
            s += __shfl_xor(s, 16);
            s += __shfl_xor(s, 32);
            if (lane < 16) atomicAdd(&dt_sum[n], s);
        }
    } else {
        const float* bias = region ? b_g : b_x;
        ushort* out = region ? g_out : u_out;
        #pragma unroll
        for (int j = 0; j < 4; j++) {
            int n = nc0 + j * 16 + fr;
            float bj = bias[n];
            #pragma unroll
            for (int i = 0; i < 4; i++) {
                int mrow = m0 + wm * 64 + i * 16 + quad * 4;
                #pragma unroll
                for (int r = 0; r < 4; r++) {
                    float v = acc[i][j][r] + bj;
                    if (region) v = sigmoid_f(v);
                    out[(size_t)(mrow + r) * HIDDEN + n] = f2bf(v);
                }
            }
        }
    }
}

// Out projection: A = y_bf [NTOK,2048], B = Wout_bf [1024,2048];
// resid = C + b_out + x   (fp32)
__global__ __launch_bounds__(256) void gemm_out(
    const ushort* __restrict__ ybf, const ushort* __restrict__ Wout,
    const float* __restrict__ b_out, const float* __restrict__ x,
    float* __restrict__ resid)
{
    __shared__ ushort As[128 * 32];
    __shared__ ushort Bs[128 * 32];
    const int tid = threadIdx.x, lane = tid & 63, w = tid >> 6;
    const int wm = w & 1, wn = w >> 1;
    const int m0 = blockIdx.y * 128, n0 = blockIdx.x * 128;
    const int quad = lane >> 4, fr = lane & 15;

    f32x4 acc[4][4];
    #pragma unroll
    for (int i = 0; i < 4; i++)
        #pragma unroll
        for (int j = 0; j < 4; j++)
            acc[i][j] = (f32x4){0.f, 0.f, 0.f, 0.f};

    kloop_128(ybf, Wout, HIDDEN, m0, n0, As, Bs, acc, lane, w, wm, wn);

    #pragma unroll
    for (int j = 0; j < 4; j++) {
        int n = n0 + wn * 64 + j * 16 + fr;
        float bj = b_out[n];
        #pragma unroll
        for (int i = 0; i < 4; i++) {
            int mrow = m0 + wm * 64 + i * 16 + quad * 4;
            #pragma unroll
            for (int r = 0; r < 4; r++) {
                size_t off = (size_t)(mrow + r) * D_MODEL + n;
                resid[off] = acc[i][j][r] + bj + x[off];
            }
        }
    }
}

__global__ __launch_bounds__(256) void dt_finalize(
    const float* __restrict__ dt_sum, const float* __restrict__ A_raw,
    const float* __restrict__ B_ssm, float* __restrict__ A_d,
    float* __restrict__ B_d, float* __restrict__ A_dL)
{
    int i = blockIdx.x * 256 + threadIdx.x;
    if (i >= HIDDEN * D_STATE) return;
    int h = i >> 4;
    float dt = dt_sum[h] * (1.0f / NTOK);
    dt = fminf(fmaxf(dt, 1e-3f), 2.0f);
    float Av = -softplus_f(A_raw[i]);
    float Ad = expf(Av * dt);
    float Bd = (Ad - 1.0f) / (Av + 1e-6f) * B_ssm[i];
    A_d[i] = Ad;
    B_d[i] = Bd;
    A_dL[i] = expf(Av * dt * CHUNK);
}

// Pass 1 (fused conv+gate+local scan): per-(b,chunk,h) thread.
// uc = u*g + (conv3(u)+conv_b)*(1-g) computed on the fly from bf16 u,g.
__global__ __launch_bounds__(256) void scan_pass1(
    const ushort* __restrict__ u_bf, const ushort* __restrict__ g_bf,
    const float* __restrict__ conv_w, const float* __restrict__ conv_b,
    const float* __restrict__ A_d, const float* __restrict__ B_d,
    const float* __restrict__ C_ssm,
    float* __restrict__ ypart, float* __restrict__ states)
{
    int idx = blockIdx.x * 256 + threadIdx.x;
    int h  = idx & (HIDDEN - 1);
    int bc = idx >> 11;
    int c  = bc & (NCHUNK - 1);
    int b  = bc >> 5;
    float Ad[D_STATE], Bd[D_STATE], Cv[D_STATE], st[D_STATE];
    const float4* a4 = reinterpret_cast<const float4*>(A_d  + h * D_STATE);
    const float4* b4 = reinterpret_cast<const float4*>(B_d  + h * D_STATE);
    const float4* c4 = reinterpret_cast<const float4*>(C_ssm + h * D_STATE);
    #pragma unroll
    for (int q = 0; q < 4; q++) {
        float4 av = a4[q], bv = b4[q], cv = c4[q];
        Ad[q*4+0]=av.x; Ad[q*4+1]=av.y; Ad[q*4+2]=av.z; Ad[q*4+3]=av.w;
        Bd[q*4+0]=bv.x; Bd[q*4+1]=bv.y; Bd[q*4+2]=bv.z; Bd[q*4+3]=bv.w;
        Cv[q*4+0]=cv.x; Cv[q*4+1]=cv.y; Cv[q*4+2]=cv.z; Cv[q*4+3]=cv.w;
    }
    #pragma unroll
    for (int s = 0; s < D_STATE; s++) st[s] = 0.f;

    float w0 = conv_w[h * 3 + 0], w1 = conv_w[h * 3 + 1];
    float w2 = conv_w[h * 3 + 2], cb = conv_b[h];
    const int tok0 = c * CHUNK;
    const size_t base = ((size_t)b * SEQ + tok0) * HIDDEN + h;
    float u_prev = (tok0 > 0) ? bf2f(u_bf[base - HIDDEN]) : 0.f;
    float u_cur  = bf2f(u_bf[base]);
    for (int l = 0; l < CHUNK; l++) {
        float u_next = (tok0 + l + 1 < SEQ) ? bf2f(u_bf[base + (size_t)(l + 1) * HIDDEN]) : 0.f;
        float gv = bf2f(g_bf[base + (size_t)l * HIDDEN]);
        float conv = u_prev * w0 + u_cur * w1 + u_next * w2 + cb;
        float uv = u_cur * gv + conv * (1.0f - gv);
        float yv = 0.f;
        #pragma unroll
        for (int s = 0; s < D_STATE; s++) {
            st[s] = fmaf(Ad[s], st[s], Bd[s] * uv);
            yv = fmaf(st[s], Cv[s], yv);
        }
        ypart[base + (size_t)l * HIDDEN] = yv;
        u_prev = u_cur; u_cur = u_next;
    }
    float4* sp = reinterpret_cast<float4*>(states + ((size_t)bc * HIDDEN + h) * D_STATE);
    #pragma unroll
    for (int q = 0; q < 4; q++)
        sp[q] = (float4){st[q*4+0], st[q*4+1], st[q*4+2], st[q*4+3]};
}

// Pass 2: in-place exclusive propagation of chunk-boundary states.
__global__ __launch_bounds__(256) void scan_pass2(
    float* __restrict__ states, const float* __restrict__ A_dL)
{
    int idx = blockIdx.x * 256 + threadIdx.x;
    int s = idx & 15;
    int h = (idx >> 4) & (HIDDEN - 1);
    int b = idx >> 15;
    float aL = A_dL[h * D_STATE + s];
    float carry = 0.f;
    for (int c = 0; c < NCHUNK; c++) {
        size_t addr = (((size_t)(b * NCHUNK + c) * HIDDEN) + h) * D_STATE + s;
        float fin = states[addr];
        states[addr] = carry;
        carry = fmaf(aL, carry, fin);
    }
}

// Pass 3: y = ypart + sum_s C*A_d^(l+1)*s_in ; emit bf16 for the out-GEMM.
__global__ __launch_bounds__(256) void scan_pass3(
    const float* __restrict__ ypart, const float* __restrict__ states,
    const float* __restrict__ A_d, const float* __restrict__ C_ssm,
    ushort* __restrict__ ybf)
{
    int idx = blockIdx.x * 256 + threadIdx.x;
    int h  = idx & (HIDDEN - 1);
    int bc = idx >> 11;
    int c  = bc & (NCHUNK - 1);
    int b  = bc >> 5;
    float Ad[D_STATE], t[D_STATE];
    const float* sp = states + ((size_t)bc * HIDDEN + h) * D_STATE;
    #pragma unroll
    for (int s = 0; s < D_STATE; s++) {
        float a = A_d[h * D_STATE + s];
        Ad[s] = a;
        t[s] = C_ssm[h * D_STATE + s] * a * sp[s];
    }
    const size_t base = ((size_t)b * SEQ + (size_t)c * CHUNK) * HIDDEN + h;
    for (int l = 0; l < CHUNK; l++) {
        float corr = 0.f;
        #pragma unroll
        for (int s = 0; s < D_STATE; s++) {
            corr += t[s];
            t[s] *= Ad[s];
        }
        ybf[base + (size_t)l * HIDDEN] = f2bf(ypart[base + (size_t)l * HIDDEN] + corr);
    }
}

__global__ __launch_bounds__(256) void ln_kernel(
    const float* __restrict__ resid, const float* __restrict__ ln_g,
    const float* __restrict__ ln_b, float* __restrict__ out)
{
    int row = blockIdx.x;
    int tid = threadIdx.x;
    const float4 v = reinterpret_cast<const float4*>(resid + (size_t)row * D_MODEL)[tid];
    float s  = v.x + v.y + v.z + v.w;
    float ss = v.x * v.x + v.y * v.y + v.z * v.z + v.w * v.w;
    #pragma unroll
    for (int off = 32; off > 0; off >>= 1) {
        s  += __shfl_down(s, off);
        ss += __shfl_down(ss, off);
    }
    __shared__ float sbuf[4], ssbuf[4];
    int wid = tid >> 6, lane = tid & 63;
    if (lane == 0) { sbuf[wid] = s; ssbuf[wid] = ss; }
    __syncthreads();
    float tot  = sbuf[0] + sbuf[1] + sbuf[2] + sbuf[3];
    float tot2 = ssbuf[0] + ssbuf[1] + ssbuf[2] + ssbuf[3];
    float mean = tot * (1.0f / D_MODEL);
    float var  = tot2 * (1.0f / D_MODEL) - mean * mean;
    float rstd = rsqrtf(var + 1e-5f);
    const float4 gv = reinterpret_cast<const float4*>(ln_g)[tid];
    const float4 bv = reinterpret_cast<const float4*>(ln_b)[tid];
    float4 o;
    o.x = (v.x - mean) * rstd * gv.x + bv.x;
    o.y = (v.y - mean) * rstd * gv.y + bv.y;
    o.z = (v.z - mean) * rstd * gv.z + bv.z;
    o.w = (v.w - mean) * rstd * gv.w + bv.w;
    reinterpret_cast<float4*>(out + (size_t)row * D_MODEL)[tid] = o;
}

extern "C" void kernel_launch(void* const* d_in, const int* in_sizes, int n_in,
                              void* d_out, int out_size, void* d_ws, size_t ws_size,
                              hipStream_t stream) {
    const float* x      = (const float*)d_in[0];
    const float* W_x    = (const float*)d_in[1];
    const float* b_x    = (const float*)d_in[2];
    const float* W_g    = (const float*)d_in[3];
    const float* b_g    = (const float*)d_in[4];
    const float* conv_w = (const float*)d_in[5];
    const float* conv_b = (const float*)d_in[6];
    const float* A_raw  = (const float*)d_in[7];
    const float* B_ssm  = (const float*)d_in[8];
    const float* C_ssm  = (const float*)d_in[9];
    const float* W_dt   = (const float*)d_in[10];
    const float* b_dt   = (const float*)d_in[11];
    const float* W_out  = (const float*)d_in[12];
    const float* b_out  = (const float*)d_in[13];
    const float* ln_g   = (const float*)d_in[14];
    const float* ln_b   = (const float*)d_in[15];

    char* W = (char*)d_ws;
    ushort* arena   = (ushort*)(W);                    // 24MB: x_bf|Wcat|Wout_bf
    ushort* x_bf    = arena;                           // [4096,1024]
    ushort* Wcat    = arena + 4194304;                 // [6144,1024] (Wx|Wg|Wdt)
    ushort* Wout_bf = arena + 10485760;                // [1024,2048]
    ushort* u_bf    = (ushort*)(W + (24ull << 20));    // 16MB [4096,2048] -> y_bf
    ushort* g_bf    = (ushort*)(W + (40ull << 20));    // 16MB [4096,2048]
    float*  ypart   = (float*)(W + (56ull << 20));     // 32MB -> resid
    float*  states  = (float*)(W + (88ull << 20));     // 8MB [B*NC,H,16]
    float*  dt_sum  = (float*)(W + (96ull << 20));     // 8KB
    float*  A_d     = (float*)(W + (96ull << 20) + 65536);
    float*  B_d     = (float*)(W + (96ull << 20) + 65536 + 131072);
    float*  A_dL    = (float*)(W + (96ull << 20) + 65536 + 262144);
    ushort* y_bf    = u_bf;                            // alias (u dead after pass1)
    float*  resid   = ypart;                           // alias (ypart dead after pass3)

    hipMemsetAsync(dt_sum, 0, HIDDEN * sizeof(float), stream);

    dim3 blk(256);
    cvt_all<<<12288, blk, 0, stream>>>(x, W_x, W_g, W_dt, W_out, arena);

    dim3 grid_proj(3 * HIDDEN / 128, NTOK / 128);   // 48 x 32
    proj_gemm_fused<<<grid_proj, blk, 0, stream>>>(x_bf, Wcat, b_x, b_g, b_dt,
                                                   u_bf, g_bf, dt_sum);
    dt_finalize<<<(HIDDEN * D_STATE) / 256, blk, 0, stream>>>(dt_sum, A_raw, B_ssm,
                                                              A_d, B_d, A_dL);
    scan_pass1<<<(BATCH * NCHUNK * HIDDEN) / 256, blk, 0, stream>>>(
        u_bf, g_bf, conv_w, conv_b, A_d, B_d, C_ssm, ypart, states);
    scan_pass2<<<(BATCH * HIDDEN * D_STATE) / 256, blk, 0, stream>>>(states, A_dL);
    scan_pass3<<<(BATCH * NCHUNK * HIDDEN) / 256, blk, 0, stream>>>(ypart, states, A_d,
                                                                    C_ssm, y_bf);
    dim3 grid_out(D_MODEL / 128, NTOK / 128);       // 8 x 32
    gemm_out<<<grid_out, blk, 0, stream>>>(y_bf, Wout_bf, b_out, x, resid);
    ln_kernel<<<NTOK, blk, 0, stream>>>(resid, ln_g, ln_b, (float*)d_out);
}